// Round 1
// baseline (1785.667 us; speedup 1.0000x reference)
//
#include <hip/hip_runtime.h>
#include <hip/hip_cooperative_groups.h>

namespace cg = cooperative_groups;

// Problem constants: B=64, E=1024, M=16, N_STEP=32, G=32000, L=8192
typedef unsigned short u16;
typedef __attribute__((ext_vector_type(4))) float  float4v;
typedef __attribute__((ext_vector_type(8))) short  short8;   // bf16x8 MFMA frag (per guide)
typedef __attribute__((ext_vector_type(4))) u16    ushort4v;

__device__ inline u16 f2bf(float f){
  unsigned u = __builtin_bit_cast(unsigned int, f);
  u += 0x7fffu + ((u >> 16) & 1u);          // RNE
  return (u16)(u >> 16);
}
__device__ inline float bf2f(u16 h){
  unsigned u = ((unsigned)h) << 16;
  return __builtin_bit_cast(float, u);
}
__device__ inline short8 pack8s(float4v a, float4v b, float s){
  short8 r;
  r[0]=(short)f2bf(a[0]*s); r[1]=(short)f2bf(a[1]*s); r[2]=(short)f2bf(a[2]*s); r[3]=(short)f2bf(a[3]*s);
  r[4]=(short)f2bf(b[0]*s); r[5]=(short)f2bf(b[1]*s); r[6]=(short)f2bf(b[2]*s); r[7]=(short)f2bf(b[3]*s);
  return r;
}
// reduce sum of s and q across a 256-thread block
__device__ inline void blockReduce2(float& s, float& q, float* sh){
  for (int m=32;m>=1;m>>=1){ s += __shfl_xor(s,m,64); q += __shfl_xor(q,m,64); }
  __syncthreads();
  if ((threadIdx.x&63)==0){ int w=threadIdx.x>>6; sh[w]=s; sh[4+w]=q; }
  __syncthreads();
  s = sh[0]+sh[1]+sh[2]+sh[3];
  q = sh[4]+sh[5]+sh[6]+sh[7];
}

// ---------------- init: zero atomic targets ----------------
__global__ void k_init(float* __restrict__ stats, float* __restrict__ rowsum,
                       float* __restrict__ picked){
  int i = blockIdx.x*256 + threadIdx.x;
  if (i < 33*64*2) stats[i] = 0.f;
  if (i < 2048){ rowsum[i] = 0.f; picked[i] = 0.f; }
}

// ---------------- fp32 -> bf16 bulk convert ----------------
__global__ void k_cvt(const float* __restrict__ src, u16* __restrict__ dst, int n4){
  int i = blockIdx.x*256 + threadIdx.x;
  if (i < n4){
    float4v v = ((const float4v*)src)[i];
    ushort4v o;
    o[0]=f2bf(v[0]); o[1]=f2bf(v[1]); o[2]=f2bf(v[2]); o[3]=f2bf(v[3]);
    ((ushort4v*)dst)[i] = o;
  }
}

// ---------------- gather + stdnorm + noise ----------------
__global__ void k_prep(const int* __restrict__ zi, const float* __restrict__ latent,
                       const float* __restrict__ noise, float* __restrict__ z0,
                       float* __restrict__ zbuf, float* __restrict__ stats){
  __shared__ float sh[8];
  int b = blockIdx.x;
  const float* lat = latent + (size_t)zi[b]*2048;
  for (int j=0;j<2;j++){
    float s=0.f,q=0.f;
    for (int e=threadIdx.x;e<1024;e+=256){ float v=lat[j*1024+e]; s+=v; q+=v*v; }
    blockReduce2(s,q,sh);
    float sd = sqrtf(fmaxf(0.f,(q - s*s*(1.f/1024.f))*(1.f/1023.f)));
    float fac = 0.113f/(1e-5f+sd);
    float zs=0.f, zq=0.f;
    for (int e=threadIdx.x;e<1024;e+=256){
      float v = lat[j*1024+e]*fac + (noise[((size_t)b*2+j)*1024+e]-0.5f)*0.05f;
      if (j==0) z0[b*1024+e]=v;
      else { zbuf[b*1024+e]=v; zs+=v; zq+=v*v; }
    }
    if (j==1){
      blockReduce2(zs,zq,sh);
      if (threadIdx.x==0){ stats[b*2]=zs; stats[b*2+1]=zq; }
    }
  }
}

// ---------------- ek/ev projection: (64 x 16384) = z0 @ Wt, MFMA ----------------
__global__ __launch_bounds__(256) void k_ekev(const float* __restrict__ z0,
    const float* __restrict__ ekw, const float* __restrict__ ekb,
    const float* __restrict__ evw, const float* __restrict__ evb,
    float* __restrict__ ek_raw, float* __restrict__ ev_raw){
  int nb = blockIdx.x;
  const float* wsrc; const float* bsrc; float* dst;
  if (nb < 1024){ wsrc=ekw; bsrc=ekb; dst=ek_raw; }
  else          { wsrc=evw; bsrc=evb; dst=ev_raw; nb -= 1024; }
  int colbase = nb*16;
  int w = threadIdx.x>>6, lane = threadIdx.x&63;
  int m16 = lane&15, q = lane>>4;
  const float* za = z0 + (w*16+m16)*1024 + q*8;
  const float* wb = wsrc + ((size_t)(colbase+m16))*1024 + q*8;
  float4v acc = {0.f,0.f,0.f,0.f};
  for (int kk=0;kk<32;kk++){
    float4v a0 = *(const float4v*)(za + kk*32);
    float4v a1 = *(const float4v*)(za + kk*32 + 4);
    float4v b0 = *(const float4v*)(wb + kk*32);
    float4v b1 = *(const float4v*)(wb + kk*32 + 4);
    short8 af = pack8s(a0,a1,1.f);
    short8 bf = pack8s(b0,b1,1.f);
    acc = __builtin_amdgcn_mfma_f32_16x16x32_bf16(af,bf,acc,0,0,0);
  }
  float bias = bsrc[colbase+m16];
  for (int reg=0;reg<4;reg++){
    int r = w*16 + q*4 + reg;                       // batch row
    dst[(size_t)r*16384 + colbase + m16] = acc[reg] + bias;
  }
}

// ---------------- per-(b,m) stdnorm -> bf16 ----------------
__global__ void k_norm(const float* __restrict__ ek_raw, const float* __restrict__ ev_raw,
                       u16* __restrict__ ek16, u16* __restrict__ ev16){
  __shared__ float sh[8];
  int rr = blockIdx.x;
  const float* src = (rr<1024)? ek_raw : ev_raw;
  u16* dst = (rr<1024)? ek16 : ev16;
  int r = rr & 1023;                                 // r = b*16+m; raw row offset = r*1024
  const float* x = src + (size_t)r*1024;
  float s=0.f,q=0.f;
  for (int e=threadIdx.x;e<1024;e+=256){ float v=x[e]; s+=v; q+=v*v; }
  blockReduce2(s,q,sh);
  float fac = 0.113f/(1e-5f+sqrtf(fmaxf(0.f,(q-s*s*(1.f/1024.f))*(1.f/1023.f))));
  u16* o = dst + (size_t)r*1024;
  for (int e=threadIdx.x;e<1024;e+=256) o[e] = f2bf(x[e]*fac);
}

// ---------------- scan: z_{t+1} = (stdnorm(z_t) @ Wt + b)/2, cooperative ----------------
// 64 blocks x 256 thr; block nb owns output cols [16nb,16nb+16) (W slice 32KB -> L1-hot).
// 1 grid.sync per step; stdnorm stats via atomics into stats[t+1].
__global__ __launch_bounds__(256) void k_scan(const u16* __restrict__ W16,
     const float* __restrict__ tb, float* __restrict__ zbuf,
     float* __restrict__ stats, u16* __restrict__ zn_all){
  cg::grid_group grid = cg::this_grid();
  __shared__ float fac[64];
  int nb = blockIdx.x;
  int colbase = nb*16;
  int w = threadIdx.x>>6, lane = threadIdx.x&63;
  int m16 = lane&15, q = lane>>4;
  const u16* wbp = W16 + ((size_t)(colbase+m16))*1024 + q*8;
  float bias = tb[colbase+m16];
  for (int t=0;t<32;t++){
    float* zin  = zbuf + (t&1)*(64*1024);
    float* zout = zbuf + ((t+1)&1)*(64*1024);
    if (threadIdx.x<64){
      float s = stats[(t*64+threadIdx.x)*2], qq = stats[(t*64+threadIdx.x)*2+1];
      fac[threadIdx.x] = 0.113f/(1e-5f+sqrtf(fmaxf(0.f,(qq-s*s*(1.f/1024.f))*(1.f/1023.f))));
    }
    __syncthreads();
    { // store zn_t slice (cols of this block) for the emit kernel
      int rr = threadIdx.x>>2;
      int c0 = colbase + (threadIdx.x&3)*4;
      float f = fac[rr];
      const float* zp = zin + rr*1024 + c0;
      u16* zo = zn_all + ((size_t)t*64+rr)*1024 + c0;
      for (int u=0;u<4;u++) zo[u] = f2bf(zp[u]*f);
    }
    int arow = w*16+m16;
    float afac = fac[arow];
    const float* za = zin + arow*1024 + q*8;
    float4v acc = {0.f,0.f,0.f,0.f};
    for (int kk=0;kk<32;kk++){
      float4v a0 = *(const float4v*)(za+kk*32);
      float4v a1 = *(const float4v*)(za+kk*32+4);
      short8 af = pack8s(a0,a1,afac);
      short8 bf = *(const short8*)(wbp + kk*32);
      acc = __builtin_amdgcn_mfma_f32_16x16x32_bf16(af,bf,acc,0,0,0);
    }
    for (int reg=0;reg<4;reg++){
      int r = w*16 + q*4 + reg;
      float v = (acc[reg]+bias)*0.5f;
      zout[r*1024 + colbase + m16] = v;
      float s1=v, s2=v*v;
      for (int mm=1;mm<16;mm<<=1){ s1 += __shfl_xor(s1,mm,16); s2 += __shfl_xor(s2,mm,16); }
      if (m16==0){
        atomicAdd(&stats[((t+1)*64+r)*2],   s1);
        atomicAdd(&stats[((t+1)*64+r)*2+1], s2);
      }
    }
    grid.sync();
  }
}

// ---------------- attention + emit for all (b,t): zs row = b*32+t ----------------
__global__ __launch_bounds__(256) void k_emit(const u16* __restrict__ zn_all,
   const u16* __restrict__ ek16, const u16* __restrict__ ev16, u16* __restrict__ zs16){
  __shared__ float part[16][5];
  __shared__ float att[16];
  __shared__ float scr[16];
  int bid = blockIdx.x;
  int b = bid>>5, t = bid&31;
  int tid = threadIdx.x, wid = tid>>6, lane = tid&63;
  const u16* zn = zn_all + ((size_t)t*64+b)*1024;
  float z0_=bf2f(zn[tid*4+0]), z1_=bf2f(zn[tid*4+1]), z2_=bf2f(zn[tid*4+2]), z3_=bf2f(zn[tid*4+3]);
  for (int m=0;m<16;m++){
    const u16* er = ek16 + ((size_t)(b*16+m))*1024 + tid*4;
    float p = z0_*bf2f(er[0]) + z1_*bf2f(er[1]) + z2_*bf2f(er[2]) + z3_*bf2f(er[3]);
    for (int mm=32;mm>=1;mm>>=1) p += __shfl_xor(p,mm,64);
    if (lane==0) part[m][wid]=p;
  }
  __syncthreads();
  if (tid<16) scr[tid] = part[tid][0]+part[tid][1]+part[tid][2]+part[tid][3];
  __syncthreads();
  if (tid==0){
    float mx=scr[0];
    for (int m=1;m<16;m++) mx=fmaxf(mx,scr[m]);
    float s=0.f, ex[16];
    for (int m=0;m<16;m++){ ex[m]=__expf(scr[m]-mx); s+=ex[m]; }
    float inv=1.f/s;
    for (int m=0;m<16;m++) att[m]=ex[m]*inv;
  }
  __syncthreads();
  float o0=0,o1=0,o2=0,o3=0;
  for (int m=0;m<16;m++){
    float a = att[m];
    const u16* vr = ev16 + ((size_t)(b*16+m))*1024 + tid*4;
    o0 += a*bf2f(vr[0]); o1 += a*bf2f(vr[1]); o2 += a*bf2f(vr[2]); o3 += a*bf2f(vr[3]);
  }
  u16* dst = zs16 + (size_t)bid*1024 + tid*4;
  dst[0]=f2bf(o0); dst[1]=f2bf(o1); dst[2]=f2bf(o2); dst[3]=f2bf(o3);
}

// ---------------- logits GEMM 2048x32000x1024 bf16 + fused logsumexp epilogue ----
// 128x128 tile, BK=64, global_load_lds(16B) with XOR-swizzled chunk map:
// chunk c = row*8 + (kq ^ (row&7))  -> coalesced 128B/row loads AND conflict-free
// ds_read_b128 fragment reads.
__global__ __launch_bounds__(256) void k_logits(const u16* __restrict__ A,
    const u16* __restrict__ Bt, const float* __restrict__ vb,
    const int* __restrict__ y, float* __restrict__ rowsum, float* __restrict__ picked){
  __shared__ u16 sA[128*64];
  __shared__ u16 sB[128*64];
  int bm = blockIdx.x, bn = blockIdx.y;
  int tid = threadIdx.x;
  int w = tid>>6, lane = tid&63;
  int wm = w>>1, wn = w&1, m16 = lane&15, q = lane>>4;
  const u16* Ab = A + (size_t)bm*128*1024;
  const u16* Bb = Bt + (size_t)bn*128*1024;
  float4v acc[4][4];
  for (int i=0;i<4;i++) for (int j=0;j<4;j++) acc[i][j] = (float4v){0.f,0.f,0.f,0.f};
  for (int kt=0;kt<16;kt++){
    int kb = kt*64;
    for (int rd=0; rd<4; rd++){
      int c = rd*256 + tid;
      int row = c>>3;
      int kq = (c&7) ^ (row&7);
      const u16* ga = Ab + (size_t)row*1024 + kb + kq*8;
      const u16* gb = Bb + (size_t)row*1024 + kb + kq*8;
      __builtin_amdgcn_global_load_lds(
          (__attribute__((address_space(1))) unsigned int*)ga,
          (__attribute__((address_space(3))) unsigned int*)&sA[c*8], 16, 0, 0);
      __builtin_amdgcn_global_load_lds(
          (__attribute__((address_space(1))) unsigned int*)gb,
          (__attribute__((address_space(3))) unsigned int*)&sB[c*8], 16, 0, 0);
    }
    __syncthreads();
    for (int s=0;s<2;s++){
      int kq = s*4 + q;
      short8 af[4], bf[4];
      for (int i=0;i<4;i++){
        int row = wm*64 + i*16 + m16;
        af[i] = *(const short8*)&sA[(row*8 + (kq ^ (row&7)))*8];
        int col = wn*64 + i*16 + m16;
        bf[i] = *(const short8*)&sB[(col*8 + (kq ^ (col&7)))*8];
      }
      for (int i=0;i<4;i++)
        for (int j=0;j<4;j++)
          acc[i][j] = __builtin_amdgcn_mfma_f32_16x16x32_bf16(af[i],bf[j],acc[i][j],0,0,0);
    }
    __syncthreads();
  }
  // epilogue: logits tiny -> exp without max-shift; per-row sum + picked scatter
  for (int i=0;i<4;i++){
    for (int reg=0;reg<4;reg++){
      int r = bm*128 + wm*64 + i*16 + q*4 + reg;
      int yt = y[r];
      float rs = 0.f;
      for (int j=0;j<4;j++){
        int g = bn*128 + wn*64 + j*16 + m16;
        float val = acc[i][j][reg] + vb[g];
        rs += __expf(val);
        if (g == yt) picked[r] = val;
      }
      for (int mm=1;mm<16;mm<<=1) rs += __shfl_xor(rs,mm,16);
      if (m16==0) atomicAdd(&rowsum[r], rs);
    }
  }
}

__global__ void k_final(const float* __restrict__ picked, const float* __restrict__ rowsum,
                        float* __restrict__ out){
  int r = blockIdx.x*256 + threadIdx.x;
  if (r < 2048) out[r] = picked[r] - logf(rowsum[r]);
}

extern "C" void kernel_launch(void* const* d_in, const int* in_sizes, int n_in,
                              void* d_out, int out_size, void* d_ws, size_t ws_size,
                              hipStream_t stream){
  (void)in_sizes; (void)n_in; (void)out_size; (void)ws_size;
  const int*   zi     = (const int*)d_in[0];
  const int*   y      = (const int*)d_in[1];
  const float* noise  = (const float*)d_in[2];
  const float* latent = (const float*)d_in[3];
  const float* transw = (const float*)d_in[4];
  const float* transb = (const float*)d_in[5];
  const float* ekw    = (const float*)d_in[6];
  const float* ekb    = (const float*)d_in[7];
  const float* evw    = (const float*)d_in[8];
  const float* evb    = (const float*)d_in[9];
  const float* vw     = (const float*)d_in[10];
  const float* vbias  = (const float*)d_in[11];
  float* out = (float*)d_out;

  // workspace layout (~89.4 MB)
  char* p = (char*)d_ws;
  u16* vocab16 = (u16*)p;   p += (size_t)32000*1024*2;
  u16* W16     = (u16*)p;   p += (size_t)1024*1024*2;
  u16* zs16    = (u16*)p;   p += (size_t)2048*1024*2;
  u16* zn16    = (u16*)p;   p += (size_t)32*64*1024*2;
  u16* ek16    = (u16*)p;   p += (size_t)64*16*1024*2;
  u16* ev16    = (u16*)p;   p += (size_t)64*16*1024*2;
  float* ekraw = (float*)p; p += (size_t)64*16384*4;
  float* evraw = (float*)p; p += (size_t)64*16384*4;
  float* z0    = (float*)p; p += (size_t)64*1024*4;
  float* zbuf  = (float*)p; p += (size_t)2*64*1024*4;
  float* stats = (float*)p; p += (size_t)33*64*2*4;
  float* rowsum= (float*)p; p += (size_t)2048*4;
  float* picked= (float*)p; p += (size_t)2048*4;

  hipLaunchKernelGGL(k_init, dim3(17), dim3(256), 0, stream, stats, rowsum, picked);
  hipLaunchKernelGGL(k_cvt,  dim3(1024),  dim3(256), 0, stream, transw, W16, 1024*1024/4);
  hipLaunchKernelGGL(k_cvt,  dim3(32000), dim3(256), 0, stream, vw, vocab16, 32000*1024/4);
  hipLaunchKernelGGL(k_prep, dim3(64),   dim3(256), 0, stream, zi, latent, noise, z0, zbuf, stats);
  hipLaunchKernelGGL(k_ekev, dim3(2048), dim3(256), 0, stream, z0, ekw, ekb, evw, evb, ekraw, evraw);
  hipLaunchKernelGGL(k_norm, dim3(2048), dim3(256), 0, stream, ekraw, evraw, ek16, ev16);
  {
    void* args[] = { (void*)&W16, (void*)&transb, (void*)&zbuf, (void*)&stats, (void*)&zn16 };
    hipLaunchCooperativeKernel((void*)k_scan, dim3(64), dim3(256), args, 0, stream);
  }
  hipLaunchKernelGGL(k_emit,   dim3(2048), dim3(256), 0, stream, zn16, ek16, ev16, zs16);
  hipLaunchKernelGGL(k_logits, dim3(16,250), dim3(256), 0, stream, zs16, vocab16, vbias, y, rowsum, picked);
  hipLaunchKernelGGL(k_final,  dim3(8), dim3(256), 0, stream, picked, rowsum, out);
}

// Round 2
// 1158.375 us; speedup vs baseline: 1.5415x; 1.5415x over previous
//
#include <hip/hip_runtime.h>
#include <hip/hip_cooperative_groups.h>

namespace cg = cooperative_groups;

// Problem constants: B=64, E=1024, M=16, N_STEP=32, G=32000, L=8192
typedef unsigned short u16;
typedef __attribute__((ext_vector_type(4))) float  float4v;
typedef __attribute__((ext_vector_type(8))) short  short8;   // bf16x8 MFMA frag
typedef __attribute__((ext_vector_type(4))) u16    ushort4v;

__device__ inline u16 f2bf(float f){
  unsigned u = __builtin_bit_cast(unsigned int, f);
  u += 0x7fffu + ((u >> 16) & 1u);          // RNE
  return (u16)(u >> 16);
}
__device__ inline float bf2f(u16 h){
  unsigned u = ((unsigned)h) << 16;
  return __builtin_bit_cast(float, u);
}
__device__ inline short8 pack8s(float4v a, float4v b, float s){
  short8 r;
  r[0]=(short)f2bf(a[0]*s); r[1]=(short)f2bf(a[1]*s); r[2]=(short)f2bf(a[2]*s); r[3]=(short)f2bf(a[3]*s);
  r[4]=(short)f2bf(b[0]*s); r[5]=(short)f2bf(b[1]*s); r[6]=(short)f2bf(b[2]*s); r[7]=(short)f2bf(b[3]*s);
  return r;
}
// reduce sum of s and q across a 256-thread block
__device__ inline void blockReduce2(float& s, float& q, float* sh){
  for (int m=32;m>=1;m>>=1){ s += __shfl_xor(s,m,64); q += __shfl_xor(q,m,64); }
  __syncthreads();
  if ((threadIdx.x&63)==0){ int w=threadIdx.x>>6; sh[w]=s; sh[4+w]=q; }
  __syncthreads();
  s = sh[0]+sh[1]+sh[2]+sh[3];
  q = sh[4]+sh[5]+sh[6]+sh[7];
}

// ---------------- init: zero atomic/flag targets ----------------
__global__ void k_init(float* __restrict__ partial, int* __restrict__ flags,
                       float* __restrict__ rowsum, float* __restrict__ picked){
  int i = blockIdx.x*256 + threadIdx.x;
  if (i < 2048) partial[i] = 0.f;     // partial[t=0] slice: 16p x 64row x 2
  if (i < 64)   flags[i] = 0;
  if (i < 2048){ rowsum[i] = 0.f; picked[i] = 0.f; }
}

// ---------------- fp32 -> bf16 bulk convert ----------------
__global__ void k_cvt(const float* __restrict__ src, u16* __restrict__ dst, int n4){
  int i = blockIdx.x*256 + threadIdx.x;
  if (i < n4){
    float4v v = ((const float4v*)src)[i];
    ushort4v o;
    o[0]=f2bf(v[0]); o[1]=f2bf(v[1]); o[2]=f2bf(v[2]); o[3]=f2bf(v[3]);
    ((ushort4v*)dst)[i] = o;
  }
}

// ---------------- gather + stdnorm + noise ----------------
// writes z0 (fp32, for ek/ev projection), zall[0] (bf16) and partial[0][p=0][b]
__global__ void k_prep(const int* __restrict__ zi, const float* __restrict__ latent,
                       const float* __restrict__ noise, float* __restrict__ z0,
                       u16* __restrict__ zall, float* __restrict__ partial){
  __shared__ float sh[8];
  int b = blockIdx.x;
  const float* lat = latent + (size_t)zi[b]*2048;
  for (int j=0;j<2;j++){
    float s=0.f,q=0.f;
    for (int e=threadIdx.x;e<1024;e+=256){ float v=lat[j*1024+e]; s+=v; q+=v*v; }
    blockReduce2(s,q,sh);
    float sd = sqrtf(fmaxf(0.f,(q - s*s*(1.f/1024.f))*(1.f/1023.f)));
    float fac = 0.113f/(1e-5f+sd);
    float zs=0.f, zq=0.f;
    for (int e=threadIdx.x;e<1024;e+=256){
      float v = lat[j*1024+e]*fac + (noise[((size_t)b*2+j)*1024+e]-0.5f)*0.05f;
      if (j==0) z0[b*1024+e]=v;
      else { zall[(size_t)b*1024+e]=f2bf(v); zs+=v; zq+=v*v; }
    }
    if (j==1){
      blockReduce2(zs,zq,sh);
      if (threadIdx.x==0){ partial[b*2]=zs; partial[b*2+1]=zq; }
    }
  }
}

// ---------------- ek/ev projection: (64 x 16384) = z0 @ Wt, MFMA ----------------
__global__ __launch_bounds__(256) void k_ekev(const float* __restrict__ z0,
    const float* __restrict__ ekw, const float* __restrict__ ekb,
    const float* __restrict__ evw, const float* __restrict__ evb,
    float* __restrict__ ek_raw, float* __restrict__ ev_raw){
  int nb = blockIdx.x;
  const float* wsrc; const float* bsrc; float* dst;
  if (nb < 1024){ wsrc=ekw; bsrc=ekb; dst=ek_raw; }
  else          { wsrc=evw; bsrc=evb; dst=ev_raw; nb -= 1024; }
  int colbase = nb*16;
  int w = threadIdx.x>>6, lane = threadIdx.x&63;
  int m16 = lane&15, q = lane>>4;
  const float* za = z0 + (w*16+m16)*1024 + q*8;
  const float* wb = wsrc + ((size_t)(colbase+m16))*1024 + q*8;
  float4v acc = {0.f,0.f,0.f,0.f};
  for (int kk=0;kk<32;kk++){
    float4v a0 = *(const float4v*)(za + kk*32);
    float4v a1 = *(const float4v*)(za + kk*32 + 4);
    float4v b0 = *(const float4v*)(wb + kk*32);
    float4v b1 = *(const float4v*)(wb + kk*32 + 4);
    short8 af = pack8s(a0,a1,1.f);
    short8 bf = pack8s(b0,b1,1.f);
    acc = __builtin_amdgcn_mfma_f32_16x16x32_bf16(af,bf,acc,0,0,0);
  }
  float bias = bsrc[colbase+m16];
  for (int reg=0;reg<4;reg++){
    int r = w*16 + q*4 + reg;                       // batch row
    dst[(size_t)r*16384 + colbase + m16] = acc[reg] + bias;
  }
}

// ---------------- per-(b,m) stdnorm -> bf16 ----------------
__global__ void k_norm(const float* __restrict__ ek_raw, const float* __restrict__ ev_raw,
                       u16* __restrict__ ek16, u16* __restrict__ ev16){
  __shared__ float sh[8];
  int rr = blockIdx.x;
  const float* src = (rr<1024)? ek_raw : ev_raw;
  u16* dst = (rr<1024)? ek16 : ev16;
  int r = rr & 1023;
  const float* x = src + (size_t)r*1024;
  float s=0.f,q=0.f;
  for (int e=threadIdx.x;e<1024;e+=256){ float v=x[e]; s+=v; q+=v*v; }
  blockReduce2(s,q,sh);
  float fac = 0.113f/(1e-5f+sqrtf(fmaxf(0.f,(q-s*s*(1.f/1024.f))*(1.f/1023.f))));
  u16* o = dst + (size_t)r*1024;
  for (int e=threadIdx.x;e<1024;e+=256) o[e] = f2bf(x[e]*fac);
}

// ---------------- scan: 4 independent groups of 16 batch rows ----------------
// Group g = batches [16g,16g+16); 16 blocks per group, block p owns output cols
// [64p, 64p+64). No grid barrier: producer-flag phaser per group.
//   zall[t][64][1024] bf16 holds raw z_t;  partial[t][16][64][2] fp32 holds
//   per-block (sum, sumsq) of z_t rows;  flags[g*16+p] = latest published step.
// stdnorm folded into epilogue: stdnorm(z)@Wt = fac_row * (z@Wt), so the K-loop
// feeds raw bf16 straight into MFMA (2 loads + 1 MFMA per iter).
__global__ __launch_bounds__(256) void k_scan(const u16* __restrict__ W16,
     const float* __restrict__ tb, u16* __restrict__ zall,
     float* __restrict__ partial, int* __restrict__ flags){
  __shared__ float ssum[16][2];
  __shared__ float fac[16];
  __shared__ float sp[16][2];
  int bid = blockIdx.x;
  int g = bid>>4, p = bid&15;
  int grow = g*16;
  int tid = threadIdx.x;
  int w = tid>>6, lane = tid&63, m16 = lane&15, q = lane>>4;
  int colbase = p*64 + w*16;
  const u16* wb = W16 + (size_t)(colbase+m16)*1024 + q*8;
  float bias = tb[colbase+m16];
  for (int t=0;t<32;t++){
    if (t>0 && tid<16){
      while (__hip_atomic_load(&flags[g*16+tid], __ATOMIC_ACQUIRE,
                               __HIP_MEMORY_SCOPE_AGENT) < t)
        __builtin_amdgcn_s_sleep(1);
    }
    __syncthreads();
    if (tid<32){
      int r=tid>>1, c=tid&1;
      float s=0.f;
      const float* pb = partial + (size_t)t*2048 + (grow+r)*2 + c;
      for (int pp=0;pp<16;pp++) s += pb[pp*128];
      ssum[r][c]=s;
      sp[r][c]=0.f;
    }
    __syncthreads();
    if (tid<16){
      float s=ssum[tid][0], qq=ssum[tid][1];
      fac[tid] = 0.113f/(1e-5f+sqrtf(fmaxf(0.f,(qq-s*s*(1.f/1024.f))*(1.f/1023.f))));
    }
    __syncthreads();
    const u16* za = zall + ((size_t)t*64 + grow + m16)*1024 + q*8;
    float4v acc = {0.f,0.f,0.f,0.f};
    #pragma unroll
    for (int kk=0;kk<32;kk++){
      short8 af = *(const short8*)(za + kk*32);
      short8 bf = *(const short8*)(wb + kk*32);
      acc = __builtin_amdgcn_mfma_f32_16x16x32_bf16(af,bf,acc,0,0,0);
    }
    u16* zo = zall + ((size_t)(t+1)*64 + grow)*1024 + colbase + m16;
    for (int reg=0;reg<4;reg++){
      int r = q*4+reg;
      float v = (acc[reg]*fac[r] + bias)*0.5f;
      zo[(size_t)r*1024] = f2bf(v);
      float s1=v, s2=v*v;
      for (int mm=1;mm<16;mm<<=1){ s1+=__shfl_xor(s1,mm,16); s2+=__shfl_xor(s2,mm,16); }
      if (m16==0){ atomicAdd(&sp[r][0],s1); atomicAdd(&sp[r][1],s2); }
    }
    __syncthreads();               // all waves' zall stores drained (vmcnt before barrier)
    if (tid<32){
      int r=tid>>1, c=tid&1;
      partial[((size_t)(t+1)*16 + p)*128 + (grow+r)*2 + c] = sp[r][c];
    }
    if (tid==0)
      __hip_atomic_store(&flags[g*16+p], t+1, __ATOMIC_RELEASE,
                         __HIP_MEMORY_SCOPE_AGENT);
  }
}

// ---------------- attention + emit for all (b,t): zs row = b*32+t ----------------
__global__ __launch_bounds__(256) void k_emit(const u16* __restrict__ zall,
   const float* __restrict__ partial,
   const u16* __restrict__ ek16, const u16* __restrict__ ev16, u16* __restrict__ zs16){
  __shared__ float part[16][5];
  __shared__ float att[16];
  __shared__ float scr[16];
  __shared__ float facsh;
  int bid = blockIdx.x;
  int b = bid>>5, t = bid&31;
  int tid = threadIdx.x, wid = tid>>6, lane = tid&63;
  if (tid==0){
    float s=0.f,qq=0.f;
    const float* pb = partial + (size_t)t*2048 + b*2;
    for (int pp=0;pp<16;pp++){ s += pb[pp*128]; qq += pb[pp*128+1]; }
    facsh = 0.113f/(1e-5f+sqrtf(fmaxf(0.f,(qq-s*s*(1.f/1024.f))*(1.f/1023.f))));
  }
  __syncthreads();
  float fac = facsh;
  const u16* zn = zall + ((size_t)t*64+b)*1024;
  float z0_=bf2f(zn[tid*4+0])*fac, z1_=bf2f(zn[tid*4+1])*fac,
        z2_=bf2f(zn[tid*4+2])*fac, z3_=bf2f(zn[tid*4+3])*fac;
  for (int m=0;m<16;m++){
    const u16* er = ek16 + ((size_t)(b*16+m))*1024 + tid*4;
    float pdot = z0_*bf2f(er[0]) + z1_*bf2f(er[1]) + z2_*bf2f(er[2]) + z3_*bf2f(er[3]);
    for (int mm=32;mm>=1;mm>>=1) pdot += __shfl_xor(pdot,mm,64);
    if (lane==0) part[m][wid]=pdot;
  }
  __syncthreads();
  if (tid<16) scr[tid] = part[tid][0]+part[tid][1]+part[tid][2]+part[tid][3];
  __syncthreads();
  if (tid==0){
    float mx=scr[0];
    for (int m=1;m<16;m++) mx=fmaxf(mx,scr[m]);
    float s=0.f, ex[16];
    for (int m=0;m<16;m++){ ex[m]=__expf(scr[m]-mx); s+=ex[m]; }
    float inv=1.f/s;
    for (int m=0;m<16;m++) att[m]=ex[m]*inv;
  }
  __syncthreads();
  float o0=0,o1=0,o2=0,o3=0;
  for (int m=0;m<16;m++){
    float a = att[m];
    const u16* vr = ev16 + ((size_t)(b*16+m))*1024 + tid*4;
    o0 += a*bf2f(vr[0]); o1 += a*bf2f(vr[1]); o2 += a*bf2f(vr[2]); o3 += a*bf2f(vr[3]);
  }
  u16* dst = zs16 + (size_t)bid*1024 + tid*4;
  dst[0]=f2bf(o0); dst[1]=f2bf(o1); dst[2]=f2bf(o2); dst[3]=f2bf(o3);
}

// ---------------- logits GEMM 2048x32000x1024 bf16 + fused logsumexp epilogue ----
__global__ __launch_bounds__(256) void k_logits(const u16* __restrict__ A,
    const u16* __restrict__ Bt, const float* __restrict__ vb,
    const int* __restrict__ y, float* __restrict__ rowsum, float* __restrict__ picked){
  __shared__ u16 sA[128*64];
  __shared__ u16 sB[128*64];
  int bm = blockIdx.x, bn = blockIdx.y;
  int tid = threadIdx.x;
  int w = tid>>6, lane = tid&63;
  int wm = w>>1, wn = w&1, m16 = lane&15, q = lane>>4;
  const u16* Ab = A + (size_t)bm*128*1024;
  const u16* Bb = Bt + (size_t)bn*128*1024;
  float4v acc[4][4];
  for (int i=0;i<4;i++) for (int j=0;j<4;j++) acc[i][j] = (float4v){0.f,0.f,0.f,0.f};
  for (int kt=0;kt<16;kt++){
    int kb = kt*64;
    for (int rd=0; rd<4; rd++){
      int c = rd*256 + tid;
      int row = c>>3;
      int kq = (c&7) ^ (row&7);
      const u16* ga = Ab + (size_t)row*1024 + kb + kq*8;
      const u16* gb = Bb + (size_t)row*1024 + kb + kq*8;
      __builtin_amdgcn_global_load_lds(
          (__attribute__((address_space(1))) unsigned int*)ga,
          (__attribute__((address_space(3))) unsigned int*)&sA[c*8], 16, 0, 0);
      __builtin_amdgcn_global_load_lds(
          (__attribute__((address_space(1))) unsigned int*)gb,
          (__attribute__((address_space(3))) unsigned int*)&sB[c*8], 16, 0, 0);
    }
    __syncthreads();
    for (int s=0;s<2;s++){
      int kq = s*4 + q;
      short8 af[4], bf[4];
      for (int i=0;i<4;i++){
        int row = wm*64 + i*16 + m16;
        af[i] = *(const short8*)&sA[(row*8 + (kq ^ (row&7)))*8];
        int col = wn*64 + i*16 + m16;
        bf[i] = *(const short8*)&sB[(col*8 + (kq ^ (col&7)))*8];
      }
      for (int i=0;i<4;i++)
        for (int j=0;j<4;j++)
          acc[i][j] = __builtin_amdgcn_mfma_f32_16x16x32_bf16(af[i],bf[j],acc[i][j],0,0,0);
    }
    __syncthreads();
  }
  for (int i=0;i<4;i++){
    for (int reg=0;reg<4;reg++){
      int r = bm*128 + wm*64 + i*16 + q*4 + reg;
      int yt = y[r];
      float rs = 0.f;
      for (int j=0;j<4;j++){
        int gcol = bn*128 + wn*64 + j*16 + m16;
        float val = acc[i][j][reg] + vb[gcol];
        rs += __expf(val);
        if (gcol == yt) picked[r] = val;
      }
      for (int mm=1;mm<16;mm<<=1) rs += __shfl_xor(rs,mm,16);
      if (m16==0) atomicAdd(&rowsum[r], rs);
    }
  }
}

__global__ void k_final(const float* __restrict__ picked, const float* __restrict__ rowsum,
                        float* __restrict__ out){
  int r = blockIdx.x*256 + threadIdx.x;
  if (r < 2048) out[r] = picked[r] - logf(rowsum[r]);
}

extern "C" void kernel_launch(void* const* d_in, const int* in_sizes, int n_in,
                              void* d_out, int out_size, void* d_ws, size_t ws_size,
                              hipStream_t stream){
  (void)in_sizes; (void)n_in; (void)out_size; (void)ws_size;
  const int*   zi     = (const int*)d_in[0];
  const int*   y      = (const int*)d_in[1];
  const float* noise  = (const float*)d_in[2];
  const float* latent = (const float*)d_in[3];
  const float* transw = (const float*)d_in[4];
  const float* transb = (const float*)d_in[5];
  const float* ekw    = (const float*)d_in[6];
  const float* ekb    = (const float*)d_in[7];
  const float* evw    = (const float*)d_in[8];
  const float* evb    = (const float*)d_in[9];
  const float* vw     = (const float*)d_in[10];
  const float* vbias  = (const float*)d_in[11];
  float* out = (float*)d_out;

  // workspace layout
  char* p = (char*)d_ws;
  u16* vocab16 = (u16*)p;   p += (size_t)32000*1024*2;
  u16* W16     = (u16*)p;   p += (size_t)1024*1024*2;
  u16* zs16    = (u16*)p;   p += (size_t)2048*1024*2;
  u16* zall    = (u16*)p;   p += (size_t)33*64*1024*2;
  u16* ek16    = (u16*)p;   p += (size_t)64*16*1024*2;
  u16* ev16    = (u16*)p;   p += (size_t)64*16*1024*2;
  float* ekraw = (float*)p; p += (size_t)64*16384*4;
  float* evraw = (float*)p; p += (size_t)64*16384*4;
  float* z0    = (float*)p; p += (size_t)64*1024*4;
  float* partial=(float*)p; p += (size_t)33*16*64*2*4;
  int*   flags = (int*)p;   p += (size_t)64*4;
  float* rowsum= (float*)p; p += (size_t)2048*4;
  float* picked= (float*)p; p += (size_t)2048*4;

  hipLaunchKernelGGL(k_init, dim3(8), dim3(256), 0, stream, partial, flags, rowsum, picked);
  hipLaunchKernelGGL(k_cvt,  dim3(1024),  dim3(256), 0, stream, transw, W16, 1024*1024/4);
  hipLaunchKernelGGL(k_cvt,  dim3(32000), dim3(256), 0, stream, vw, vocab16, 32000*1024/4);
  hipLaunchKernelGGL(k_prep, dim3(64),   dim3(256), 0, stream, zi, latent, noise, z0, zall, partial);
  hipLaunchKernelGGL(k_ekev, dim3(2048), dim3(256), 0, stream, z0, ekw, ekb, evw, evb, ekraw, evraw);
  hipLaunchKernelGGL(k_norm, dim3(2048), dim3(256), 0, stream, ekraw, evraw, ek16, ev16);
  {
    void* args[] = { (void*)&W16, (void*)&transb, (void*)&zall, (void*)&partial, (void*)&flags };
    hipLaunchCooperativeKernel((void*)k_scan, dim3(64), dim3(256), args, 0, stream);
  }
  hipLaunchKernelGGL(k_emit,   dim3(2048), dim3(256), 0, stream, zall, partial, ek16, ev16, zs16);
  hipLaunchKernelGGL(k_logits, dim3(16,250), dim3(256), 0, stream, zs16, vocab16, vbias, y, rowsum, picked);
  hipLaunchKernelGGL(k_final,  dim3(8), dim3(256), 0, stream, picked, rowsum, out);
}

// Round 3
// 1056.829 us; speedup vs baseline: 1.6896x; 1.0961x over previous
//
#include <hip/hip_runtime.h>
#include <hip/hip_cooperative_groups.h>

namespace cg = cooperative_groups;

// Problem constants: B=64, E=1024, M=16, N_STEP=32, G=32000, L=8192
typedef unsigned short u16;
typedef unsigned long long ull;
typedef __attribute__((ext_vector_type(4))) float  float4v;
typedef __attribute__((ext_vector_type(8))) short  short8;   // bf16x8 MFMA frag
typedef __attribute__((ext_vector_type(4))) u16    ushort4v;
typedef __attribute__((ext_vector_type(2))) ull    ull2;
typedef __attribute__((ext_vector_type(4))) unsigned int uint4v;

__device__ inline u16 f2bf(float f){
  unsigned u = __builtin_bit_cast(unsigned int, f);
  u += 0x7fffu + ((u >> 16) & 1u);          // RNE
  return (u16)(u >> 16);
}
__device__ inline float bf2f(u16 h){
  unsigned u = ((unsigned)h) << 16;
  return __builtin_bit_cast(float, u);
}
__device__ inline short8 pack8s(float4v a, float4v b, float s){
  short8 r;
  r[0]=(short)f2bf(a[0]*s); r[1]=(short)f2bf(a[1]*s); r[2]=(short)f2bf(a[2]*s); r[3]=(short)f2bf(a[3]*s);
  r[4]=(short)f2bf(b[0]*s); r[5]=(short)f2bf(b[1]*s); r[6]=(short)f2bf(b[2]*s); r[7]=(short)f2bf(b[3]*s);
  return r;
}
// reduce sum of s and q across a 256-thread block
__device__ inline void blockReduce2(float& s, float& q, float* sh){
  for (int m=32;m>=1;m>>=1){ s += __shfl_xor(s,m,64); q += __shfl_xor(q,m,64); }
  __syncthreads();
  if ((threadIdx.x&63)==0){ int w=threadIdx.x>>6; sh[w]=s; sh[4+w]=q; }
  __syncthreads();
  s = sh[0]+sh[1]+sh[2]+sh[3];
  q = sh[4]+sh[5]+sh[6]+sh[7];
}

// ---------------- init: zero atomic/flag targets ----------------
__global__ void k_init(float* __restrict__ partial, int* __restrict__ cnt,
                       float* __restrict__ rowsum, float* __restrict__ picked){
  int i = blockIdx.x*256 + threadIdx.x;
  if (i < 2048) partial[i] = 0.f;      // partial[t=0] slice: 16p x 64row x 2
  if (i < 4*33) cnt[i] = ((i%33)==0) ? 16 : 0;   // step-0 pre-released
  if (i < 2048){ rowsum[i] = 0.f; picked[i] = 0.f; }
}

// ---------------- fp32 -> bf16 bulk convert ----------------
__global__ void k_cvt(const float* __restrict__ src, u16* __restrict__ dst, int n4){
  int i = blockIdx.x*256 + threadIdx.x;
  if (i < n4){
    float4v v = ((const float4v*)src)[i];
    ushort4v o;
    o[0]=f2bf(v[0]); o[1]=f2bf(v[1]); o[2]=f2bf(v[2]); o[3]=f2bf(v[3]);
    ((ushort4v*)dst)[i] = o;
  }
}

// ---------------- gather + stdnorm + noise ----------------
__global__ void k_prep(const int* __restrict__ zi, const float* __restrict__ latent,
                       const float* __restrict__ noise, float* __restrict__ z0,
                       u16* __restrict__ zall, float* __restrict__ partial){
  __shared__ float sh[8];
  int b = blockIdx.x;
  const float* lat = latent + (size_t)zi[b]*2048;
  for (int j=0;j<2;j++){
    float s=0.f,q=0.f;
    for (int e=threadIdx.x;e<1024;e+=256){ float v=lat[j*1024+e]; s+=v; q+=v*v; }
    blockReduce2(s,q,sh);
    float sd = sqrtf(fmaxf(0.f,(q - s*s*(1.f/1024.f))*(1.f/1023.f)));
    float fac = 0.113f/(1e-5f+sd);
    float zs=0.f, zq=0.f;
    for (int e=threadIdx.x;e<1024;e+=256){
      float v = lat[j*1024+e]*fac + (noise[((size_t)b*2+j)*1024+e]-0.5f)*0.05f;
      if (j==0) z0[b*1024+e]=v;
      else { zall[(size_t)b*1024+e]=f2bf(v); zs+=v; zq+=v*v; }
    }
    if (j==1){
      blockReduce2(zs,zq,sh);
      if (threadIdx.x==0){ partial[b*2]=zs; partial[b*2+1]=zq; }
    }
  }
}

// ---------------- ek/ev projection: (64 x 16384) = z0 @ Wt, MFMA ----------------
__global__ __launch_bounds__(256) void k_ekev(const float* __restrict__ z0,
    const float* __restrict__ ekw, const float* __restrict__ ekb,
    const float* __restrict__ evw, const float* __restrict__ evb,
    float* __restrict__ ek_raw, float* __restrict__ ev_raw){
  int nb = blockIdx.x;
  const float* wsrc; const float* bsrc; float* dst;
  if (nb < 1024){ wsrc=ekw; bsrc=ekb; dst=ek_raw; }
  else          { wsrc=evw; bsrc=evb; dst=ev_raw; nb -= 1024; }
  int colbase = nb*16;
  int w = threadIdx.x>>6, lane = threadIdx.x&63;
  int m16 = lane&15, q = lane>>4;
  const float* za = z0 + (w*16+m16)*1024 + q*8;
  const float* wb = wsrc + ((size_t)(colbase+m16))*1024 + q*8;
  float4v acc = {0.f,0.f,0.f,0.f};
  for (int kk=0;kk<32;kk++){
    float4v a0 = *(const float4v*)(za + kk*32);
    float4v a1 = *(const float4v*)(za + kk*32 + 4);
    float4v b0 = *(const float4v*)(wb + kk*32);
    float4v b1 = *(const float4v*)(wb + kk*32 + 4);
    short8 af = pack8s(a0,a1,1.f);
    short8 bf = pack8s(b0,b1,1.f);
    acc = __builtin_amdgcn_mfma_f32_16x16x32_bf16(af,bf,acc,0,0,0);
  }
  float bias = bsrc[colbase+m16];
  for (int reg=0;reg<4;reg++){
    int r = w*16 + q*4 + reg;                       // batch row
    dst[(size_t)r*16384 + colbase + m16] = acc[reg] + bias;
  }
}

// ---------------- per-(b,m) stdnorm -> bf16 ----------------
__global__ void k_norm(const float* __restrict__ ek_raw, const float* __restrict__ ev_raw,
                       u16* __restrict__ ek16, u16* __restrict__ ev16){
  __shared__ float sh[8];
  int rr = blockIdx.x;
  const float* src = (rr<1024)? ek_raw : ev_raw;
  u16* dst = (rr<1024)? ek16 : ev16;
  int r = rr & 1023;
  const float* x = src + (size_t)r*1024;
  float s=0.f,q=0.f;
  for (int e=threadIdx.x;e<1024;e+=256){ float v=x[e]; s+=v; q+=v*v; }
  blockReduce2(s,q,sh);
  float fac = 0.113f/(1e-5f+sqrtf(fmaxf(0.f,(q-s*s*(1.f/1024.f))*(1.f/1023.f))));
  u16* o = dst + (size_t)r*1024;
  for (int e=threadIdx.x;e<1024;e+=256) o[e] = f2bf(x[e]*fac);
}

// ---------------- scan: 4 groups x 16 blocks; W slice in LDS; no fences ----------
// Block (g,p): batches [16g,16g+16), output cols [64p,64p+64).
// All cross-block traffic (zall, partial, cnt) uses RELAXED agent-scope atomics
// (global ... sc1: bypasses non-coherent L1/L2, coherent at Infinity Cache).
// W slice staged ONCE into LDS (XOR-swizzled) -> zero per-step W traffic and
// no buffer_inv/buffer_wbl2 on the critical path.
__global__ __launch_bounds__(256) void k_scan(const u16* __restrict__ W16,
     const float* __restrict__ tb, u16* __restrict__ zall,
     float* __restrict__ partial, int* __restrict__ cnt){
  __shared__ u16 sW[64*1024];            // 128 KB W slice, swizzled
  __shared__ float fac[16];
  __shared__ float sp[16][2];
  __shared__ u16 zstage[16][64];
  int bid = blockIdx.x;
  int g = bid>>4, p = bid&15;
  int grow = g*16;
  int colbase = p*64;
  int tid = threadIdx.x;
  int w = tid>>6, lane = tid&63, m16 = lane&15, q = lane>>4;
  int rw = w*16 + m16;

  // stage W slice: rows r (=col colbase+r), 128 chunks of 8 bf16; swizzle low3
  for (int i = tid; i < 8192; i += 256){
    int r = i>>7, c = i&127;
    int cs = (c & ~7) | ((c&7) ^ (r&7));
    *(uint4v*)&sW[(r*128 + cs)*8] =
        *(const uint4v*)(W16 + (size_t)(colbase+r)*1024 + c*8);
  }
  float bias = tb[colbase + rw];
  __syncthreads();

  for (int t=0;t<32;t++){
    // wait for all 16 producers of step t (step 0 pre-released by k_init)
    if (tid==0){
      while (__hip_atomic_load(&cnt[g*33+t], __ATOMIC_RELAXED, __HIP_MEMORY_SCOPE_AGENT) < 16)
        __builtin_amdgcn_s_sleep(1);
    }
    __syncthreads();
    // parallel stats read: 256 threads cover 16p x 16r, reduce over p via shfl
    {
      int pp = tid&15, r = tid>>4;
      float* pb = (float*)(partial + ((size_t)t*16 + pp)*128 + (grow + r)*2);
      float s  = __hip_atomic_load(pb+0, __ATOMIC_RELAXED, __HIP_MEMORY_SCOPE_AGENT);
      float qq = __hip_atomic_load(pb+1, __ATOMIC_RELAXED, __HIP_MEMORY_SCOPE_AGENT);
      for (int mm=1;mm<16;mm<<=1){ s += __shfl_xor(s,mm,64); qq += __shfl_xor(qq,mm,64); }
      if (pp==0)
        fac[r] = 0.113f/(1e-5f+sqrtf(fmaxf(0.f,(qq - s*s*(1.f/1024.f))*(1.f/1023.f))));
      if (tid<32) sp[tid>>1][tid&1] = 0.f;
    }
    // preload all A-fragments (coherent 8B loads, fully independent)
    u16* za = (u16*)(zall + ((size_t)t*64 + grow + m16)*1024);
    ull a0[32], a1[32];
    #pragma unroll
    for (int kk=0;kk<32;kk++){
      a0[kk] = __hip_atomic_load((ull*)(za + kk*32 + q*8),     __ATOMIC_RELAXED, __HIP_MEMORY_SCOPE_AGENT);
      a1[kk] = __hip_atomic_load((ull*)(za + kk*32 + q*8 + 4), __ATOMIC_RELAXED, __HIP_MEMORY_SCOPE_AGENT);
    }
    __syncthreads();   // fac + sp-zero visible
    float4v acc = {0.f,0.f,0.f,0.f};
    #pragma unroll
    for (int kk=0;kk<32;kk++){
      ull2 av; av[0]=a0[kk]; av[1]=a1[kk];
      short8 af = __builtin_bit_cast(short8, av);
      int c = kk*4 + q;
      int cs = (c & ~7) | ((c&7) ^ (rw&7));
      short8 bf = *(const short8*)&sW[(rw*128 + cs)*8];
      acc = __builtin_amdgcn_mfma_f32_16x16x32_bf16(af,bf,acc,0,0,0);
    }
    // epilogue: scale by fac, add bias, halve; stage to LDS; per-row stats
    #pragma unroll
    for (int reg=0;reg<4;reg++){
      int r = q*4 + reg;
      float v = (acc[reg]*fac[r] + bias)*0.5f;
      zstage[r][rw] = f2bf(v);
      float s1=v, s2=v*v;
      for (int mm=1;mm<16;mm<<=1){ s1+=__shfl_xor(s1,mm,64); s2+=__shfl_xor(s2,mm,64); }
      if (m16==0){ atomicAdd(&sp[r][0],s1); atomicAdd(&sp[r][1],s2); }
    }
    __syncthreads();
    // publish z slice (coherent 8B stores) + partial stats
    {
      int r = tid>>4, cq = (tid&15)*4;
      ull val = *(const ull*)&zstage[r][cq];
      __hip_atomic_store((ull*)(zall + ((size_t)(t+1)*64 + grow + r)*1024 + colbase + cq),
                         val, __ATOMIC_RELAXED, __HIP_MEMORY_SCOPE_AGENT);
      if (tid < 32){
        int rr2 = tid>>1, cc = tid&1;
        __hip_atomic_store(partial + ((size_t)(t+1)*16 + p)*128 + (grow+rr2)*2 + cc,
                           sp[rr2][cc], __ATOMIC_RELAXED, __HIP_MEMORY_SCOPE_AGENT);
      }
    }
    __syncthreads();   // per-wave vmcnt(0) drain before barrier -> stores visible
    if (tid==0)
      (void)__hip_atomic_fetch_add(&cnt[g*33+t+1], 1, __ATOMIC_RELEASE, __HIP_MEMORY_SCOPE_AGENT);
  }
}

// ---------------- attention + emit for all (b,t): zs row = b*32+t ----------------
__global__ __launch_bounds__(256) void k_emit(const u16* __restrict__ zall,
   const float* __restrict__ partial,
   const u16* __restrict__ ek16, const u16* __restrict__ ev16, u16* __restrict__ zs16){
  __shared__ float part[16][5];
  __shared__ float att[16];
  __shared__ float scr[16];
  __shared__ float facsh;
  int bid = blockIdx.x;
  int b = bid>>5, t = bid&31;
  int tid = threadIdx.x, wid = tid>>6, lane = tid&63;
  if (tid==0){
    float s=0.f,qq=0.f;
    const float* pb = partial + (size_t)t*2048 + b*2;
    for (int pp=0;pp<16;pp++){ s += pb[pp*128]; qq += pb[pp*128+1]; }
    facsh = 0.113f/(1e-5f+sqrtf(fmaxf(0.f,(qq-s*s*(1.f/1024.f))*(1.f/1023.f))));
  }
  __syncthreads();
  float fac = facsh;
  const u16* zn = zall + ((size_t)t*64+b)*1024;
  float z0_=bf2f(zn[tid*4+0])*fac, z1_=bf2f(zn[tid*4+1])*fac,
        z2_=bf2f(zn[tid*4+2])*fac, z3_=bf2f(zn[tid*4+3])*fac;
  for (int m=0;m<16;m++){
    const u16* er = ek16 + ((size_t)(b*16+m))*1024 + tid*4;
    float pdot = z0_*bf2f(er[0]) + z1_*bf2f(er[1]) + z2_*bf2f(er[2]) + z3_*bf2f(er[3]);
    for (int mm=32;mm>=1;mm>>=1) pdot += __shfl_xor(pdot,mm,64);
    if (lane==0) part[m][wid]=pdot;
  }
  __syncthreads();
  if (tid<16) scr[tid] = part[tid][0]+part[tid][1]+part[tid][2]+part[tid][3];
  __syncthreads();
  if (tid==0){
    float mx=scr[0];
    for (int m=1;m<16;m++) mx=fmaxf(mx,scr[m]);
    float s=0.f, ex[16];
    for (int m=0;m<16;m++){ ex[m]=__expf(scr[m]-mx); s+=ex[m]; }
    float inv=1.f/s;
    for (int m=0;m<16;m++) att[m]=ex[m]*inv;
  }
  __syncthreads();
  float o0=0,o1=0,o2=0,o3=0;
  for (int m=0;m<16;m++){
    float a = att[m];
    const u16* vr = ev16 + ((size_t)(b*16+m))*1024 + tid*4;
    o0 += a*bf2f(vr[0]); o1 += a*bf2f(vr[1]); o2 += a*bf2f(vr[2]); o3 += a*bf2f(vr[3]);
  }
  u16* dst = zs16 + (size_t)bid*1024 + tid*4;
  dst[0]=f2bf(o0); dst[1]=f2bf(o1); dst[2]=f2bf(o2); dst[3]=f2bf(o3);
}

// ---------------- logits GEMM 2048x32000x1024 bf16 + fused logsumexp epilogue ----
__global__ __launch_bounds__(256) void k_logits(const u16* __restrict__ A,
    const u16* __restrict__ Bt, const float* __restrict__ vb,
    const int* __restrict__ y, float* __restrict__ rowsum, float* __restrict__ picked){
  __shared__ u16 sA[128*64];
  __shared__ u16 sB[128*64];
  int bm = blockIdx.x, bn = blockIdx.y;
  int tid = threadIdx.x;
  int w = tid>>6, lane = tid&63;
  int wm = w>>1, wn = w&1, m16 = lane&15, q = lane>>4;
  const u16* Ab = A + (size_t)bm*128*1024;
  const u16* Bb = Bt + (size_t)bn*128*1024;
  float4v acc[4][4];
  for (int i=0;i<4;i++) for (int j=0;j<4;j++) acc[i][j] = (float4v){0.f,0.f,0.f,0.f};
  for (int kt=0;kt<16;kt++){
    int kb = kt*64;
    for (int rd=0; rd<4; rd++){
      int c = rd*256 + tid;
      int row = c>>3;
      int kq = (c&7) ^ (row&7);
      const u16* ga = Ab + (size_t)row*1024 + kb + kq*8;
      const u16* gb = Bb + (size_t)row*1024 + kb + kq*8;
      __builtin_amdgcn_global_load_lds(
          (__attribute__((address_space(1))) unsigned int*)ga,
          (__attribute__((address_space(3))) unsigned int*)&sA[c*8], 16, 0, 0);
      __builtin_amdgcn_global_load_lds(
          (__attribute__((address_space(1))) unsigned int*)gb,
          (__attribute__((address_space(3))) unsigned int*)&sB[c*8], 16, 0, 0);
    }
    __syncthreads();
    for (int s=0;s<2;s++){
      int kq = s*4 + q;
      short8 af[4], bf[4];
      for (int i=0;i<4;i++){
        int row = wm*64 + i*16 + m16;
        af[i] = *(const short8*)&sA[(row*8 + (kq ^ (row&7)))*8];
        int col = wn*64 + i*16 + m16;
        bf[i] = *(const short8*)&sB[(col*8 + (kq ^ (col&7)))*8];
      }
      for (int i=0;i<4;i++)
        for (int j=0;j<4;j++)
          acc[i][j] = __builtin_amdgcn_mfma_f32_16x16x32_bf16(af[i],bf[j],acc[i][j],0,0,0);
    }
    __syncthreads();
  }
  for (int i=0;i<4;i++){
    for (int reg=0;reg<4;reg++){
      int r = bm*128 + wm*64 + i*16 + q*4 + reg;
      int yt = y[r];
      float rs = 0.f;
      for (int j=0;j<4;j++){
        int gcol = bn*128 + wn*64 + j*16 + m16;
        float val = acc[i][j][reg] + vb[gcol];
        rs += __expf(val);
        if (gcol == yt) picked[r] = val;
      }
      for (int mm=1;mm<16;mm<<=1) rs += __shfl_xor(rs,mm,16);
      if (m16==0) atomicAdd(&rowsum[r], rs);
    }
  }
}

__global__ void k_final(const float* __restrict__ picked, const float* __restrict__ rowsum,
                        float* __restrict__ out){
  int r = blockIdx.x*256 + threadIdx.x;
  if (r < 2048) out[r] = picked[r] - logf(rowsum[r]);
}

extern "C" void kernel_launch(void* const* d_in, const int* in_sizes, int n_in,
                              void* d_out, int out_size, void* d_ws, size_t ws_size,
                              hipStream_t stream){
  (void)in_sizes; (void)n_in; (void)out_size; (void)ws_size;
  const int*   zi     = (const int*)d_in[0];
  const int*   y      = (const int*)d_in[1];
  const float* noise  = (const float*)d_in[2];
  const float* latent = (const float*)d_in[3];
  const float* transw = (const float*)d_in[4];
  const float* transb = (const float*)d_in[5];
  const float* ekw    = (const float*)d_in[6];
  const float* ekb    = (const float*)d_in[7];
  const float* evw    = (const float*)d_in[8];
  const float* evb    = (const float*)d_in[9];
  const float* vw     = (const float*)d_in[10];
  const float* vbias  = (const float*)d_in[11];
  float* out = (float*)d_out;

  // workspace layout
  char* p = (char*)d_ws;
  u16* vocab16 = (u16*)p;   p += (size_t)32000*1024*2;
  u16* W16     = (u16*)p;   p += (size_t)1024*1024*2;
  u16* zs16    = (u16*)p;   p += (size_t)2048*1024*2;
  u16* zall    = (u16*)p;   p += (size_t)33*64*1024*2;
  u16* ek16    = (u16*)p;   p += (size_t)64*16*1024*2;
  u16* ev16    = (u16*)p;   p += (size_t)64*16*1024*2;
  float* ekraw = (float*)p; p += (size_t)64*16384*4;
  float* evraw = (float*)p; p += (size_t)64*16384*4;
  float* z0    = (float*)p; p += (size_t)64*1024*4;
  float* partial=(float*)p; p += (size_t)33*16*64*2*4;
  int*   cnt   = (int*)p;   p += (size_t)4*33*4;
  float* rowsum= (float*)p; p += (size_t)2048*4;
  float* picked= (float*)p; p += (size_t)2048*4;

  hipLaunchKernelGGL(k_init, dim3(8), dim3(256), 0, stream, partial, cnt, rowsum, picked);
  hipLaunchKernelGGL(k_cvt,  dim3(1024),  dim3(256), 0, stream, transw, W16, 1024*1024/4);
  hipLaunchKernelGGL(k_cvt,  dim3(32000), dim3(256), 0, stream, vw, vocab16, 32000*1024/4);
  hipLaunchKernelGGL(k_prep, dim3(64),   dim3(256), 0, stream, zi, latent, noise, z0, zall, partial);
  hipLaunchKernelGGL(k_ekev, dim3(2048), dim3(256), 0, stream, z0, ekw, ekb, evw, evb, ekraw, evraw);
  hipLaunchKernelGGL(k_norm, dim3(2048), dim3(256), 0, stream, ekraw, evraw, ek16, ev16);
  {
    void* args[] = { (void*)&W16, (void*)&transb, (void*)&zall, (void*)&partial, (void*)&cnt };
    hipLaunchCooperativeKernel((void*)k_scan, dim3(64), dim3(256), args, 0, stream);
  }
  hipLaunchKernelGGL(k_emit,   dim3(2048), dim3(256), 0, stream, zall, partial, ek16, ev16, zs16);
  hipLaunchKernelGGL(k_logits, dim3(16,250), dim3(256), 0, stream, zs16, vocab16, vbias, y, rowsum, picked);
  hipLaunchKernelGGL(k_final,  dim3(8), dim3(256), 0, stream, picked, rowsum, out);
}

// Round 5
// 1045.526 us; speedup vs baseline: 1.7079x; 1.0108x over previous
//
#include <hip/hip_runtime.h>
#include <hip/hip_cooperative_groups.h>

namespace cg = cooperative_groups;

// Problem constants: B=64, E=1024, M=16, N_STEP=32, G=32000, L=8192
typedef unsigned short u16;
typedef unsigned long long ull;
typedef __attribute__((ext_vector_type(4))) float  float4v;
typedef __attribute__((ext_vector_type(8))) short  short8;   // bf16x8 MFMA frag
typedef __attribute__((ext_vector_type(4))) u16    ushort4v;
typedef __attribute__((ext_vector_type(2))) ull    ull2;
typedef __attribute__((ext_vector_type(4))) unsigned int uint4v;

__device__ inline u16 f2bf(float f){
  unsigned u = __builtin_bit_cast(unsigned int, f);
  u += 0x7fffu + ((u >> 16) & 1u);          // RNE
  return (u16)(u >> 16);
}
__device__ inline float bf2f(u16 h){
  unsigned u = ((unsigned)h) << 16;
  return __builtin_bit_cast(float, u);
}
__device__ inline short8 pack8s(float4v a, float4v b, float s){
  short8 r;
  r[0]=(short)f2bf(a[0]*s); r[1]=(short)f2bf(a[1]*s); r[2]=(short)f2bf(a[2]*s); r[3]=(short)f2bf(a[3]*s);
  r[4]=(short)f2bf(b[0]*s); r[5]=(short)f2bf(b[1]*s); r[6]=(short)f2bf(b[2]*s); r[7]=(short)f2bf(b[3]*s);
  return r;
}
// reduce sum of s and q across a 256-thread block
__device__ inline void blockReduce2(float& s, float& q, float* sh){
  for (int m=32;m>=1;m>>=1){ s += __shfl_xor(s,m,64); q += __shfl_xor(q,m,64); }
  __syncthreads();
  if ((threadIdx.x&63)==0){ int w=threadIdx.x>>6; sh[w]=s; sh[4+w]=q; }
  __syncthreads();
  s = sh[0]+sh[1]+sh[2]+sh[3];
  q = sh[4]+sh[5]+sh[6]+sh[7];
}

// ---------------- init: zero atomic/flag targets ----------------
__global__ void k_init(float* __restrict__ partial, int* __restrict__ cnt,
                       float* __restrict__ rowsum, float* __restrict__ picked){
  int i = blockIdx.x*256 + threadIdx.x;
  if (i < 2048) partial[i] = 0.f;      // partial[t=0] slice: 16p x 64row x 2
  if (i < 4*33) cnt[i] = ((i%33)==0) ? 16 : 0;   // step-0 pre-released
  if (i < 2048){ rowsum[i] = 0.f; picked[i] = 0.f; }
}

// ---------------- fp32 -> bf16 bulk convert ----------------
__global__ void k_cvt(const float* __restrict__ src, u16* __restrict__ dst, int n4){
  int i = blockIdx.x*256 + threadIdx.x;
  if (i < n4){
    float4v v = ((const float4v*)src)[i];
    ushort4v o;
    o[0]=f2bf(v[0]); o[1]=f2bf(v[1]); o[2]=f2bf(v[2]); o[3]=f2bf(v[3]);
    ((ushort4v*)dst)[i] = o;
  }
}

// ---------------- gather + stdnorm + noise ----------------
__global__ void k_prep(const int* __restrict__ zi, const float* __restrict__ latent,
                       const float* __restrict__ noise, float* __restrict__ z0,
                       u16* __restrict__ zall, float* __restrict__ partial){
  __shared__ float sh[8];
  int b = blockIdx.x;
  const float* lat = latent + (size_t)zi[b]*2048;
  for (int j=0;j<2;j++){
    float s=0.f,q=0.f;
    for (int e=threadIdx.x;e<1024;e+=256){ float v=lat[j*1024+e]; s+=v; q+=v*v; }
    blockReduce2(s,q,sh);
    float sd = sqrtf(fmaxf(0.f,(q - s*s*(1.f/1024.f))*(1.f/1023.f)));
    float fac = 0.113f/(1e-5f+sd);
    float zs=0.f, zq=0.f;
    for (int e=threadIdx.x;e<1024;e+=256){
      float v = lat[j*1024+e]*fac + (noise[((size_t)b*2+j)*1024+e]-0.5f)*0.05f;
      if (j==0) z0[b*1024+e]=v;
      else { zall[(size_t)b*1024+e]=f2bf(v); zs+=v; zq+=v*v; }
    }
    if (j==1){
      blockReduce2(zs,zq,sh);
      if (threadIdx.x==0){ partial[b*2]=zs; partial[b*2+1]=zq; }
    }
  }
}

// ---------------- ek/ev projection: (64 x 16384) = z0 @ Wt, MFMA ----------------
__global__ __launch_bounds__(256) void k_ekev(const float* __restrict__ z0,
    const float* __restrict__ ekw, const float* __restrict__ ekb,
    const float* __restrict__ evw, const float* __restrict__ evb,
    float* __restrict__ ek_raw, float* __restrict__ ev_raw){
  int nb = blockIdx.x;
  const float* wsrc; const float* bsrc; float* dst;
  if (nb < 1024){ wsrc=ekw; bsrc=ekb; dst=ek_raw; }
  else          { wsrc=evw; bsrc=evb; dst=ev_raw; nb -= 1024; }
  int colbase = nb*16;
  int w = threadIdx.x>>6, lane = threadIdx.x&63;
  int m16 = lane&15, q = lane>>4;
  const float* za = z0 + (w*16+m16)*1024 + q*8;
  const float* wb = wsrc + ((size_t)(colbase+m16))*1024 + q*8;
  float4v acc = {0.f,0.f,0.f,0.f};
  for (int kk=0;kk<32;kk++){
    float4v a0 = *(const float4v*)(za + kk*32);
    float4v a1 = *(const float4v*)(za + kk*32 + 4);
    float4v b0 = *(const float4v*)(wb + kk*32);
    float4v b1 = *(const float4v*)(wb + kk*32 + 4);
    short8 af = pack8s(a0,a1,1.f);
    short8 bf = pack8s(b0,b1,1.f);
    acc = __builtin_amdgcn_mfma_f32_16x16x32_bf16(af,bf,acc,0,0,0);
  }
  float bias = bsrc[colbase+m16];
  for (int reg=0;reg<4;reg++){
    int r = w*16 + q*4 + reg;                       // batch row
    dst[(size_t)r*16384 + colbase + m16] = acc[reg] + bias;
  }
}

// ---------------- per-(b,m) stdnorm -> bf16 ----------------
__global__ void k_norm(const float* __restrict__ ek_raw, const float* __restrict__ ev_raw,
                       u16* __restrict__ ek16, u16* __restrict__ ev16){
  __shared__ float sh[8];
  int rr = blockIdx.x;
  const float* src = (rr<1024)? ek_raw : ev_raw;
  u16* dst = (rr<1024)? ek16 : ev16;
  int r = rr & 1023;
  const float* x = src + (size_t)r*1024;
  float s=0.f,q=0.f;
  for (int e=threadIdx.x;e<1024;e+=256){ float v=x[e]; s+=v; q+=v*v; }
  blockReduce2(s,q,sh);
  float fac = 0.113f/(1e-5f+sqrtf(fmaxf(0.f,(q-s*s*(1.f/1024.f))*(1.f/1023.f))));
  u16* o = dst + (size_t)r*1024;
  for (int e=threadIdx.x;e<1024;e+=256) o[e] = f2bf(x[e]*fac);
}

// ---------------- scan: 4 groups x 16 blocks; W slice in LDS; no fences ----------
// Round-5 change vs round-3: producer flag fetch_add is RELAXED (not RELEASE).
// RELEASE emitted buffer_wbl2 sc1 (full per-XCD L2 writeback walk) once per
// block per step = 512 walks on the critical chain, yet was functionally a
// no-op: all published data goes out as sc1 write-through stores (never dirty
// in L2) and __syncthreads()'s vmcnt(0) drain already guarantees they reached
// the L3 coherence point before thread 0 issues the flag RMW.
__global__ __launch_bounds__(256) void k_scan(const u16* __restrict__ W16,
     const float* __restrict__ tb, u16* __restrict__ zall,
     float* __restrict__ partial, int* __restrict__ cnt){
  __shared__ u16 sW[64*1024];            // 128 KB W slice, swizzled
  __shared__ float fac[16];
  __shared__ float sp[16][2];
  __shared__ u16 zstage[16][64];
  int bid = blockIdx.x;
  int g = bid>>4, p = bid&15;
  int grow = g*16;
  int colbase = p*64;
  int tid = threadIdx.x;
  int w = tid>>6, lane = tid&63, m16 = lane&15, q = lane>>4;
  int rw = w*16 + m16;

  // stage W slice: rows r (=col colbase+r), 128 chunks of 8 bf16; swizzle low3
  for (int i = tid; i < 8192; i += 256){
    int r = i>>7, c = i&127;
    int cs = (c & ~7) | ((c&7) ^ (r&7));
    *(uint4v*)&sW[(r*128 + cs)*8] =
        *(const uint4v*)(W16 + (size_t)(colbase+r)*1024 + c*8);
  }
  float bias = tb[colbase + rw];
  __syncthreads();

  for (int t=0;t<32;t++){
    // wait for all 16 producers of step t (step 0 pre-released by k_init)
    if (tid==0){
      while (__hip_atomic_load(&cnt[g*33+t], __ATOMIC_RELAXED, __HIP_MEMORY_SCOPE_AGENT) < 16)
        __builtin_amdgcn_s_sleep(1);
    }
    __syncthreads();
    // parallel stats read: 256 threads cover 16p x 16r, reduce over p via shfl
    {
      int pp = tid&15, r = tid>>4;
      float* pb = (float*)(partial + ((size_t)t*16 + pp)*128 + (grow + r)*2);
      float s  = __hip_atomic_load(pb+0, __ATOMIC_RELAXED, __HIP_MEMORY_SCOPE_AGENT);
      float qq = __hip_atomic_load(pb+1, __ATOMIC_RELAXED, __HIP_MEMORY_SCOPE_AGENT);
      for (int mm=1;mm<16;mm<<=1){ s += __shfl_xor(s,mm,64); qq += __shfl_xor(qq,mm,64); }
      if (pp==0)
        fac[r] = 0.113f/(1e-5f+sqrtf(fmaxf(0.f,(qq - s*s*(1.f/1024.f))*(1.f/1023.f))));
      if (tid<32) sp[tid>>1][tid&1] = 0.f;
    }
    // preload all A-fragments (coherent 8B loads, fully independent)
    u16* za = (u16*)(zall + ((size_t)t*64 + grow + m16)*1024);
    ull a0[32], a1[32];
    #pragma unroll
    for (int kk=0;kk<32;kk++){
      a0[kk] = __hip_atomic_load((ull*)(za + kk*32 + q*8),     __ATOMIC_RELAXED, __HIP_MEMORY_SCOPE_AGENT);
      a1[kk] = __hip_atomic_load((ull*)(za + kk*32 + q*8 + 4), __ATOMIC_RELAXED, __HIP_MEMORY_SCOPE_AGENT);
    }
    __syncthreads();   // fac + sp-zero visible
    float4v acc = {0.f,0.f,0.f,0.f};
    #pragma unroll
    for (int kk=0;kk<32;kk++){
      ull2 av; av[0]=a0[kk]; av[1]=a1[kk];
      short8 af = __builtin_bit_cast(short8, av);
      int c = kk*4 + q;
      int cs = (c & ~7) | ((c&7) ^ (rw&7));
      short8 bf = *(const short8*)&sW[(rw*128 + cs)*8];
      acc = __builtin_amdgcn_mfma_f32_16x16x32_bf16(af,bf,acc,0,0,0);
    }
    // epilogue: scale by fac, add bias, halve; stage to LDS; per-row stats
    #pragma unroll
    for (int reg=0;reg<4;reg++){
      int r = q*4 + reg;
      float v = (acc[reg]*fac[r] + bias)*0.5f;
      zstage[r][rw] = f2bf(v);
      float s1=v, s2=v*v;
      for (int mm=1;mm<16;mm<<=1){ s1+=__shfl_xor(s1,mm,64); s2+=__shfl_xor(s2,mm,64); }
      if (m16==0){ atomicAdd(&sp[r][0],s1); atomicAdd(&sp[r][1],s2); }
    }
    __syncthreads();
    // publish z slice (coherent 8B stores) + partial stats
    {
      int r = tid>>4, cq = (tid&15)*4;
      ull val = *(const ull*)&zstage[r][cq];
      __hip_atomic_store((ull*)(zall + ((size_t)(t+1)*64 + grow + r)*1024 + colbase + cq),
                         val, __ATOMIC_RELAXED, __HIP_MEMORY_SCOPE_AGENT);
      if (tid < 32){
        int rr2 = tid>>1, cc = tid&1;
        __hip_atomic_store(partial + ((size_t)(t+1)*16 + p)*128 + (grow+rr2)*2 + cc,
                           sp[rr2][cc], __ATOMIC_RELAXED, __HIP_MEMORY_SCOPE_AGENT);
      }
    }
    __syncthreads();   // per-wave vmcnt(0) drain before barrier -> stores at L3
    if (tid==0)
      (void)__hip_atomic_fetch_add(&cnt[g*33+t+1], 1, __ATOMIC_RELAXED, __HIP_MEMORY_SCOPE_AGENT);
  }
}

// ---------------- attention + emit for all (b,t): zs row = b*32+t ----------------
__global__ __launch_bounds__(256) void k_emit(const u16* __restrict__ zall,
   const float* __restrict__ partial,
   const u16* __restrict__ ek16, const u16* __restrict__ ev16, u16* __restrict__ zs16){
  __shared__ float part[16][5];
  __shared__ float att[16];
  __shared__ float scr[16];
  __shared__ float facsh;
  int bid = blockIdx.x;
  int b = bid>>5, t = bid&31;
  int tid = threadIdx.x, wid = tid>>6, lane = tid&63;
  if (tid==0){
    float s=0.f,qq=0.f;
    const float* pb = partial + (size_t)t*2048 + b*2;
    for (int pp=0;pp<16;pp++){ s += pb[pp*128]; qq += pb[pp*128+1]; }
    facsh = 0.113f/(1e-5f+sqrtf(fmaxf(0.f,(qq-s*s*(1.f/1024.f))*(1.f/1023.f))));
  }
  __syncthreads();
  float fac = facsh;
  const u16* zn = zall + ((size_t)t*64+b)*1024;
  float z0_=bf2f(zn[tid*4+0])*fac, z1_=bf2f(zn[tid*4+1])*fac,
        z2_=bf2f(zn[tid*4+2])*fac, z3_=bf2f(zn[tid*4+3])*fac;
  for (int m=0;m<16;m++){
    const u16* er = ek16 + ((size_t)(b*16+m))*1024 + tid*4;
    float pdot = z0_*bf2f(er[0]) + z1_*bf2f(er[1]) + z2_*bf2f(er[2]) + z3_*bf2f(er[3]);
    for (int mm=32;mm>=1;mm>>=1) pdot += __shfl_xor(pdot,mm,64);
    if (lane==0) part[m][wid]=pdot;
  }
  __syncthreads();
  if (tid<16) scr[tid] = part[tid][0]+part[tid][1]+part[tid][2]+part[tid][3];
  __syncthreads();
  if (tid==0){
    float mx=scr[0];
    for (int m=1;m<16;m++) mx=fmaxf(mx,scr[m]);
    float s=0.f, ex[16];
    for (int m=0;m<16;m++){ ex[m]=__expf(scr[m]-mx); s+=ex[m]; }
    float inv=1.f/s;
    for (int m=0;m<16;m++) att[m]=ex[m]*inv;
  }
  __syncthreads();
  float o0=0,o1=0,o2=0,o3=0;
  for (int m=0;m<16;m++){
    float a = att[m];
    const u16* vr = ev16 + ((size_t)(b*16+m))*1024 + tid*4;
    o0 += a*bf2f(vr[0]); o1 += a*bf2f(vr[1]); o2 += a*bf2f(vr[2]); o3 += a*bf2f(vr[3]);
  }
  u16* dst = zs16 + (size_t)bid*1024 + tid*4;
  dst[0]=f2bf(o0); dst[1]=f2bf(o1); dst[2]=f2bf(o2); dst[3]=f2bf(o3);
}

// ---------------- logits GEMM 2048x32000x1024 bf16 + fused logsumexp epilogue ----
__global__ __launch_bounds__(256) void k_logits(const u16* __restrict__ A,
    const u16* __restrict__ Bt, const float* __restrict__ vb,
    const int* __restrict__ y, float* __restrict__ rowsum, float* __restrict__ picked){
  __shared__ u16 sA[128*64];
  __shared__ u16 sB[128*64];
  int bm = blockIdx.x, bn = blockIdx.y;
  int tid = threadIdx.x;
  int w = tid>>6, lane = tid&63;
  int wm = w>>1, wn = w&1, m16 = lane&15, q = lane>>4;
  const u16* Ab = A + (size_t)bm*128*1024;
  const u16* Bb = Bt + (size_t)bn*128*1024;
  float4v acc[4][4];
  for (int i=0;i<4;i++) for (int j=0;j<4;j++) acc[i][j] = (float4v){0.f,0.f,0.f,0.f};
  for (int kt=0;kt<16;kt++){
    int kb = kt*64;
    for (int rd=0; rd<4; rd++){
      int c = rd*256 + tid;
      int row = c>>3;
      int kq = (c&7) ^ (row&7);
      const u16* ga = Ab + (size_t)row*1024 + kb + kq*8;
      const u16* gb = Bb + (size_t)row*1024 + kb + kq*8;
      __builtin_amdgcn_global_load_lds(
          (__attribute__((address_space(1))) unsigned int*)ga,
          (__attribute__((address_space(3))) unsigned int*)&sA[c*8], 16, 0, 0);
      __builtin_amdgcn_global_load_lds(
          (__attribute__((address_space(1))) unsigned int*)gb,
          (__attribute__((address_space(3))) unsigned int*)&sB[c*8], 16, 0, 0);
    }
    __syncthreads();
    for (int s=0;s<2;s++){
      int kq = s*4 + q;
      short8 af[4], bf[4];
      for (int i=0;i<4;i++){
        int row = wm*64 + i*16 + m16;
        af[i] = *(const short8*)&sA[(row*8 + (kq ^ (row&7)))*8];
        int col = wn*64 + i*16 + m16;
        bf[i] = *(const short8*)&sB[(col*8 + (kq ^ (col&7)))*8];
      }
      for (int i=0;i<4;i++)
        for (int j=0;j<4;j++)
          acc[i][j] = __builtin_amdgcn_mfma_f32_16x16x32_bf16(af[i],bf[j],acc[i][j],0,0,0);
    }
    __syncthreads();
  }
  for (int i=0;i<4;i++){
    for (int reg=0;reg<4;reg++){
      int r = bm*128 + wm*64 + i*16 + q*4 + reg;
      int yt = y[r];
      float rs = 0.f;
      for (int j=0;j<4;j++){
        int gcol = bn*128 + wn*64 + j*16 + m16;
        float val = acc[i][j][reg] + vb[gcol];
        rs += __expf(val);
        if (gcol == yt) picked[r] = val;
      }
      for (int mm=1;mm<16;mm<<=1) rs += __shfl_xor(rs,mm,16);
      if (m16==0) atomicAdd(&rowsum[r], rs);
    }
  }
}

__global__ void k_final(const float* __restrict__ picked, const float* __restrict__ rowsum,
                        float* __restrict__ out){
  int r = blockIdx.x*256 + threadIdx.x;
  if (r < 2048) out[r] = picked[r] - logf(rowsum[r]);
}

extern "C" void kernel_launch(void* const* d_in, const int* in_sizes, int n_in,
                              void* d_out, int out_size, void* d_ws, size_t ws_size,
                              hipStream_t stream){
  (void)in_sizes; (void)n_in; (void)out_size; (void)ws_size;
  const int*   zi     = (const int*)d_in[0];
  const int*   y      = (const int*)d_in[1];
  const float* noise  = (const float*)d_in[2];
  const float* latent = (const float*)d_in[3];
  const float* transw = (const float*)d_in[4];
  const float* transb = (const float*)d_in[5];
  const float* ekw    = (const float*)d_in[6];
  const float* ekb    = (const float*)d_in[7];
  const float* evw    = (const float*)d_in[8];
  const float* evb    = (const float*)d_in[9];
  const float* vw     = (const float*)d_in[10];
  const float* vbias  = (const float*)d_in[11];
  float* out = (float*)d_out;

  // workspace layout
  char* p = (char*)d_ws;
  u16* vocab16 = (u16*)p;   p += (size_t)32000*1024*2;
  u16* W16     = (u16*)p;   p += (size_t)1024*1024*2;
  u16* zs16    = (u16*)p;   p += (size_t)2048*1024*2;
  u16* zall    = (u16*)p;   p += (size_t)33*64*1024*2;
  u16* ek16    = (u16*)p;   p += (size_t)64*16*1024*2;
  u16* ev16    = (u16*)p;   p += (size_t)64*16*1024*2;
  float* ekraw = (float*)p; p += (size_t)64*16384*4;
  float* evraw = (float*)p; p += (size_t)64*16384*4;
  float* z0    = (float*)p; p += (size_t)64*1024*4;
  float* partial=(float*)p; p += (size_t)33*16*64*2*4;
  int*   cnt   = (int*)p;   p += (size_t)4*33*4;
  float* rowsum= (float*)p; p += (size_t)2048*4;
  float* picked= (float*)p; p += (size_t)2048*4;

  hipLaunchKernelGGL(k_init, dim3(8), dim3(256), 0, stream, partial, cnt, rowsum, picked);
  hipLaunchKernelGGL(k_cvt,  dim3(1024),  dim3(256), 0, stream, transw, W16, 1024*1024/4);
  hipLaunchKernelGGL(k_cvt,  dim3(32000), dim3(256), 0, stream, vw, vocab16, 32000*1024/4);
  hipLaunchKernelGGL(k_prep, dim3(64),   dim3(256), 0, stream, zi, latent, noise, z0, zall, partial);
  hipLaunchKernelGGL(k_ekev, dim3(2048), dim3(256), 0, stream, z0, ekw, ekb, evw, evb, ekraw, evraw);
  hipLaunchKernelGGL(k_norm, dim3(2048), dim3(256), 0, stream, ekraw, evraw, ek16, ev16);
  {
    void* args[] = { (void*)&W16, (void*)&transb, (void*)&zall, (void*)&partial, (void*)&cnt };
    hipLaunchCooperativeKernel((void*)k_scan, dim3(64), dim3(256), args, 0, stream);
  }
  hipLaunchKernelGGL(k_emit,   dim3(2048), dim3(256), 0, stream, zall, partial, ek16, ev16, zs16);
  hipLaunchKernelGGL(k_logits, dim3(16,250), dim3(256), 0, stream, zs16, vocab16, vbias, y, rowsum, picked);
  hipLaunchKernelGGL(k_final,  dim3(8), dim3(256), 0, stream, picked, rowsum, out);
}